// Round 4
// baseline (801.504 us; speedup 1.0000x reference)
//
#include <hip/hip_runtime.h>

#define NDIM 128

// ---------------- edge-index normalization ----------------
// int64 edge_index => odd 32-bit words are 0; int32 => odd words are random
// node ids. ONE block samples 4096 edges; no global atomics (R2: full-E
// single-address atomic detection cost 108 us).
__global__ __launch_bounds__(256) void detect_kernel(
    const int* __restrict__ raw, int* __restrict__ flag, int E) {
    __shared__ int any_nz;
    if (threadIdx.x == 0) any_nz = 0;
    __syncthreads();
    int local = 0;
    const int samples = (E < 4096) ? E : 4096;
#pragma unroll
    for (int j = 0; j < 16; ++j) {
        int i = threadIdx.x * 16 + j;
        if (i < samples) local |= raw[2 * i + 1];
    }
    if (local) atomicOr(&any_nz, 1);   // LDS atomic, cheap
    __syncthreads();
    if (threadIdx.x == 0) *flag = any_nz;   // nonzero -> int32 layout
}

__global__ void convert_kernel(const int* __restrict__ raw, const int* __restrict__ flag,
                               int* __restrict__ idx, int total) {
    int i = blockIdx.x * 256 + threadIdx.x;
    if (i >= total) return;
    idx[i] = (*flag == 0) ? raw[2 * i] : raw[i];
}

// ---------------- CSR build (counting sort by dst) ----------------
__global__ void hist_kernel(const int* __restrict__ idx, int* __restrict__ deg, int E) {
    int i = blockIdx.x * 256 + threadIdx.x;
    if (i < E) atomicAdd(&deg[idx[E + i]], 1);  // dst row
}

// --- device-wide exclusive scan of deg, 3 kernels, tile = 1024 elements ---
__global__ __launch_bounds__(256) void deg_reduce_kernel(
    const int* __restrict__ deg, int* __restrict__ partials, int n) {
    const int base = blockIdx.x * 1024;
    const int tid = threadIdx.x;
    int s = 0;
#pragma unroll
    for (int j = 0; j < 4; ++j) {
        int i = base + tid * 4 + j;
        if (i < n) s += deg[i];
    }
#pragma unroll
    for (int off = 32; off; off >>= 1) s += __shfl_down(s, off);
    __shared__ int ws[4];
    if ((tid & 63) == 0) ws[tid >> 6] = s;
    __syncthreads();
    if (tid == 0) partials[blockIdx.x] = ws[0] + ws[1] + ws[2] + ws[3];
}

__global__ void scan_partials_kernel(int* __restrict__ partials, int nb,
                                     int* __restrict__ row_start, int n) {
    __shared__ int sh[1024];
    const int tid = threadIdx.x;  // 1024 threads
    int v = (tid < nb) ? partials[tid] : 0;
    sh[tid] = v;
    __syncthreads();
    for (int off = 1; off < 1024; off <<= 1) {
        int a = sh[tid];
        int b = (tid >= off) ? sh[tid - off] : 0;
        __syncthreads();
        sh[tid] = a + b;
        __syncthreads();
    }
    if (tid < nb) partials[tid] = (tid == 0) ? 0 : sh[tid - 1];  // exclusive block offset
    if (tid == 0) row_start[n] = sh[1023];                       // total edge count
}

__global__ __launch_bounds__(256) void deg_downsweep_kernel(
    const int* __restrict__ deg, const int* __restrict__ partials,
    int* __restrict__ row_start, int* __restrict__ cursor,
    float* __restrict__ inv_deg, int n) {
    const int base = blockIdx.x * 1024;
    const int tid = threadIdx.x;
    const int i0 = base + tid * 4;
    int d[4];
    int s = 0;
#pragma unroll
    for (int j = 0; j < 4; ++j) {
        int i = i0 + j;
        d[j] = (i < n) ? deg[i] : 0;
        s += d[j];
    }
    const int lane = tid & 63;
    int incl = s;
#pragma unroll
    for (int off = 1; off < 64; off <<= 1) {
        int t = __shfl_up(incl, off);
        if (lane >= off) incl += t;
    }
    __shared__ int wsum[4];
    if (lane == 63) wsum[tid >> 6] = incl;
    __syncthreads();
    int woff = 0;
    const int w = tid >> 6;
    for (int k = 0; k < w; ++k) woff += wsum[k];
    int excl = incl - s + woff + partials[blockIdx.x];
#pragma unroll
    for (int j = 0; j < 4; ++j) {
        int i = i0 + j;
        if (i < n) {
            row_start[i] = excl;
            cursor[i] = excl;
            inv_deg[i] = 1.0f / (float)max(d[j], 1);
            excl += d[j];
        }
    }
}

__global__ void scatter_kernel(const int* __restrict__ idx, int* __restrict__ cursor,
                               int* __restrict__ sorted_src, int E) {
    int i = blockIdx.x * 256 + threadIdx.x;
    if (i < E) {
        int d = idx[E + i];
        int p = atomicAdd(&cursor[d], 1);
        sorted_src[p] = idx[i];
    }
}

// ---------------- mean aggregation (CSR gather-reduce) ----------------
// 32 threads per node, each owns a float4 column slice.
__global__ __launch_bounds__(256) void aggregate_kernel(
    const float* __restrict__ x, const int* __restrict__ row_start,
    const int* __restrict__ sorted_src, const float* __restrict__ inv_deg,
    float* __restrict__ aggr, int n) {
    int gid = blockIdx.x * 256 + threadIdx.x;
    int node = gid >> 5;
    if (node >= n) return;
    int q = (gid & 31) << 2;
    int beg = row_start[node];
    int end = row_start[node + 1];
    float4 acc = make_float4(0.f, 0.f, 0.f, 0.f);
    for (int e = beg; e < end; ++e) {
        int s = sorted_src[e];
        const float4 v = *(const float4*)(x + (size_t)s * NDIM + q);
        acc.x += v.x; acc.y += v.y; acc.z += v.z; acc.w += v.w;
    }
    float inv = inv_deg[node];
    acc.x *= inv; acc.y *= inv; acc.z *= inv; acc.w *= inv;
    *(float4*)(aggr + (size_t)node * NDIM + q) = acc;
}

// ---------------- fused layer GEMM v2: Y = Ag@Wl + X@Wr + b (+relu) ----------
// 64-row x 128-col tile, 512 threads (8 waves), 4x4 acc per thread.
// R3 fixes: tx over 32 col-groups of 4 -> contiguous 16B-stride LDS reads
// (conflict-free; old tx*8 layout was 4-way, 6.8M conflict cycles) and
// 8 waves/block -> ~24 waves/CU at the 782-block grid (was 12).
__global__ __launch_bounds__(512) void gemm_kernel(
    const float* __restrict__ Ag, const float* __restrict__ X,
    const float* __restrict__ Wl, const float* __restrict__ Wr,
    const float* __restrict__ bias, float* __restrict__ Y, int n, int do_relu) {
    __shared__ float Al[16][68];    // A tiles transposed [k][row], 272B row stride (16B-aligned)
    __shared__ float Ar[16][68];
    __shared__ float Sl[16][132];   // W tiles [k][col], 528B row stride (16B-aligned)
    __shared__ float Sr[16][132];
    const int tid = threadIdx.x;
    const int tx = tid & 31;        // col group: cols tx*4 .. tx*4+3
    const int ty = tid >> 5;        // row group: rows ty*4 .. ty*4+3 (0..15)
    const int row0 = blockIdx.x * 64;
    float acc[4][4];
#pragma unroll
    for (int i = 0; i < 4; ++i)
#pragma unroll
        for (int j = 0; j < 4; ++j) acc[i][j] = 0.f;

    // A staging: 4-lane groups read contiguous 64B row segments (coalesced)
    const int smat = tid >> 8;            // 0: Ag->Al, 1: X->Ar
    const int srow = (tid >> 2) & 63;     // 0..63
    const int sk = (tid & 3) << 2;        // 0,4,8,12
    const int arow = row0 + srow;
    const float* __restrict__ Asrc = smat ? X : Ag;
    float (*At)[68] = smat ? Ar : Al;
    // W staging: each thread one float4 of Wl and Wr (contiguous per wave)
    const int wk = tid >> 5;              // 0..15
    const int wc = (tid & 31) << 2;       // 0..124

    for (int k0 = 0; k0 < NDIM; k0 += 16) {
        float4 a = make_float4(0.f, 0.f, 0.f, 0.f);
        if (arow < n) a = *(const float4*)(Asrc + (size_t)arow * NDIM + k0 + sk);
        const float4 wlv = *(const float4*)(Wl + (size_t)(k0 + wk) * NDIM + wc);
        const float4 wrv = *(const float4*)(Wr + (size_t)(k0 + wk) * NDIM + wc);
        __syncthreads();
        At[sk + 0][srow] = a.x; At[sk + 1][srow] = a.y;
        At[sk + 2][srow] = a.z; At[sk + 3][srow] = a.w;
        *(float4*)&Sl[wk][wc] = wlv;
        *(float4*)&Sr[wk][wc] = wrv;
        __syncthreads();
#pragma unroll
        for (int k = 0; k < 16; ++k) {
            const float4 av = *(const float4*)&Al[k][ty << 2];  // half-wave broadcast
            const float4 bv = *(const float4*)&Ar[k][ty << 2];
            const float4 lv = *(const float4*)&Sl[k][tx << 2];  // contiguous, conflict-free
            const float4 rv = *(const float4*)&Sr[k][tx << 2];
            const float a4[4] = {av.x, av.y, av.z, av.w};
            const float b4[4] = {bv.x, bv.y, bv.z, bv.w};
            const float l4[4] = {lv.x, lv.y, lv.z, lv.w};
            const float r4[4] = {rv.x, rv.y, rv.z, rv.w};
#pragma unroll
            for (int i = 0; i < 4; ++i)
#pragma unroll
                for (int j = 0; j < 4; ++j)
                    acc[i][j] += a4[i] * l4[j] + b4[i] * r4[j];
        }
    }

    const float4 bb = *(const float4*)(bias + (tx << 2));
    const float b4[4] = {bb.x, bb.y, bb.z, bb.w};
#pragma unroll
    for (int i = 0; i < 4; ++i) {
        const int r = row0 + (ty << 2) + i;
        if (r < n) {
            float o[4];
#pragma unroll
            for (int j = 0; j < 4; ++j) {
                o[j] = acc[i][j] + b4[j];
                if (do_relu) o[j] = fmaxf(o[j], 0.f);
            }
            *(float4*)(Y + (size_t)r * NDIM + (tx << 2)) =
                make_float4(o[0], o[1], o[2], o[3]);
        }
    }
}

// ---------------- host launcher ----------------
extern "C" void kernel_launch(void* const* d_in, const int* in_sizes, int n_in,
                              void* d_out, int out_size, void* d_ws, size_t ws_size,
                              hipStream_t stream) {
    const float* x0   = (const float*)d_in[0];
    const int*   eraw = (const int*)d_in[1];
    const float* Wl   = (const float*)d_in[2];
    const float* bl   = (const float*)d_in[3];
    const float* Wr   = (const float*)d_in[4];
    float* out = (float*)d_out;

    const int N = in_sizes[0] / NDIM;   // 50000
    const int E = in_sizes[1] / 2;      // 600000

    auto align_up = [](size_t v) { return (v + 255) & ~(size_t)255; };
    char* p = (char*)d_ws;
    int* idx = (int*)p;                 p += align_up((size_t)2 * E * 4);
    int* deg = (int*)p;                 p += align_up((size_t)(N + 1) * 4);  // deg[N] is the flag
    int* flag = deg + N;
    int* row_start = (int*)p;           p += align_up((size_t)(N + 1) * 4);
    int* cursor = (int*)p;              p += align_up((size_t)N * 4);
    int* ssrc = (int*)p;                p += align_up((size_t)E * 4);
    float* invd = (float*)p;            p += align_up((size_t)N * 4);
    int* partials = (int*)p;            p += align_up((size_t)1024 * 4);
    float* buf0 = (float*)p;            p += align_up((size_t)N * NDIM * 4);
    float* buf1 = (float*)p;            p += align_up((size_t)N * NDIM * 4);

    const int nb = (N + 1023) / 1024;   // scan tiles

    hipMemsetAsync(deg, 0, (size_t)N * 4, stream);
    detect_kernel<<<1, 256, 0, stream>>>(eraw, flag, E);
    convert_kernel<<<(2 * E + 255) / 256, 256, 0, stream>>>(eraw, flag, idx, 2 * E);
    hist_kernel<<<(E + 255) / 256, 256, 0, stream>>>(idx, deg, E);
    deg_reduce_kernel<<<nb, 256, 0, stream>>>(deg, partials, N);
    scan_partials_kernel<<<1, 1024, 0, stream>>>(partials, nb, row_start, N);
    deg_downsweep_kernel<<<nb, 256, 0, stream>>>(deg, partials, row_start, cursor, invd, N);
    scatter_kernel<<<(E + 255) / 256, 256, 0, stream>>>(idx, cursor, ssrc, E);

    const float* xin = x0;
    for (int l = 0; l < 5; ++l) {
        float* ab = (l & 1) ? buf1 : buf0;          // aggregation output
        aggregate_kernel<<<(N * 32 + 255) / 256, 256, 0, stream>>>(
            xin, row_start, ssrc, invd, ab, N);
        float* yo = (l == 4) ? out : ab;            // GEMM may safely overwrite its own A rows
        gemm_kernel<<<(N + 63) / 64, 512, 0, stream>>>(
            ab, xin, Wl + (size_t)l * NDIM * NDIM, Wr + (size_t)l * NDIM * NDIM,
            bl + (size_t)l * NDIM, yo, N, l < 4 ? 1 : 0);
        xin = yo;
    }
}